// Round 2
// baseline (2674.490 us; speedup 1.0000x reference)
//
#include <hip/hip_runtime.h>
#include <stdint.h>

typedef uint16_t u16;
typedef uint32_t u32;
typedef __attribute__((ext_vector_type(8))) short short8;
typedef __attribute__((ext_vector_type(4))) float f32x4;

// ---------- constants ----------
constexpr int B_  = 64;
constexpr int C_  = 2048;
constexpr int CI_ = 1024;
constexpr int N_  = 512;     // H*W
constexpr int CHB = 32;      // batches per chunk (2 chunks)

// ---------- bf16 helpers ----------
__device__ __forceinline__ float bf2f(u16 h){
  union{u32 u; float f;} v; v.u = ((u32)h) << 16; return v.f;
}
__device__ __forceinline__ u16 f2bf(float x){
  union{float f; u32 u;} v; v.f = x;
  u32 u = v.u;
  u32 r = u + 0x7fffu + ((u >> 16) & 1u);
  return (u16)(r >> 16);
}
__device__ __forceinline__ u32 split2(float v){
  u16 hi = f2bf(v);
  u16 lo = f2bf(v - bf2f(hi));
  return (u32)hi | ((u32)lo << 16);
}

// ---------- async global->LDS (16B per lane) ----------
__device__ __forceinline__ void gld_lds16(const void* gsrc, void* ldst){
  __builtin_amdgcn_global_load_lds(
      (__attribute__((address_space(1))) void*)(const_cast<void*>(gsrc)),
      (__attribute__((address_space(3))) void*)(ldst), 16, 0, 0);
}

// =====================================================================
// Generic NT GEMM:  Out[m][n] = sum_k A[m][k] * B[n][k]  (+ bias, fp32)
// A,B: bf16 row-major (contiguous in k).
// BIAS_MODE: 0 none, 1 per-row bias[m], 2 per-col bias[n]  (bias fp32)
// OUT_MODE : 0 bf16, 1 fp32, 2 bf16 hi/lo pair at Out[row*ldo + 2*col]
// BSPLIT   : also accumulate A * swap_pairs(B)  (hi/lo cross terms)
// Tile 128x128, BK=32, 256 threads (4 waves, 2x2 of 64x64).
// =====================================================================
template<int BIAS_MODE, int OUT_MODE, bool BSPLIT>
__global__ __launch_bounds__(256)
void gemm_nt(const u16* __restrict__ A, long aBatch, int lda,
             const u16* __restrict__ Bm, long bBatch, int ldb,
             void* __restrict__ Out, long oBatch, int ldo,
             const float* __restrict__ bias, int K)
{
  constexpr int TM = 128, TN = 128, BK = 32;
  const int bz = blockIdx.z;
  const int tm = blockIdx.x * TM;
  const int tn = blockIdx.y * TN;
  const u16* Ab = A  + (long)bz * aBatch;
  const u16* Bb = Bm + (long)bz * bBatch;

  __shared__ __align__(16) u16 As[TM * BK];
  __shared__ __align__(16) u16 Bs[TN * BK];

  const int tid  = threadIdx.x;
  const int wave = tid >> 6;
  const int lane = tid & 63;
  const int wm   = (wave & 1) << 6;
  const int wn   = (wave >> 1) << 6;
  const int lrow = lane & 15;
  const int quad = lane >> 4;

  f32x4 acc[4][4];
#pragma unroll
  for (int i = 0; i < 4; ++i)
#pragma unroll
    for (int j = 0; j < 4; ++j)
      acc[i][j] = f32x4{0.f, 0.f, 0.f, 0.f};

  for (int k0 = 0; k0 < K; k0 += BK){
#pragma unroll
    for (int it = 0; it < 2; ++it){
      const int c   = it * 256 + wave * 64 + lane;
      const int row = c >> 2;
      const int col = (c & 3) << 3;
      const u16* srcA = Ab + (long)(tm + row) * lda + k0 + col;
      const u16* srcB = Bb + (long)(tn + row) * ldb + k0 + col;
      gld_lds16(srcA, &As[(it * 256 + wave * 64) * 8]);
      gld_lds16(srcB, &Bs[(it * 256 + wave * 64) * 8]);
    }
    __syncthreads();

    short8 af[4], bfr[4];
#pragma unroll
    for (int t = 0; t < 4; ++t){
      af[t]  = *(const short8*)&As[(wm + t * 16 + lrow) * BK + quad * 8];
      bfr[t] = *(const short8*)&Bs[(wn + t * 16 + lrow) * BK + quad * 8];
    }
#pragma unroll
    for (int i = 0; i < 4; ++i)
#pragma unroll
      for (int j = 0; j < 4; ++j){
        acc[i][j] = __builtin_amdgcn_mfma_f32_16x16x32_bf16(af[i], bfr[j], acc[i][j], 0, 0, 0);
        if (BSPLIT){
          short8 bs = __builtin_shufflevector(bfr[j], bfr[j], 1, 0, 3, 2, 5, 4, 7, 6);
          acc[i][j] = __builtin_amdgcn_mfma_f32_16x16x32_bf16(af[i], bs, acc[i][j], 0, 0, 0);
        }
      }
    __syncthreads();
  }

  // epilogue: D[row][col], col=lane&15, row=quad*4+r  (verified m89/m91)
  const long obase = (long)bz * oBatch;
#pragma unroll
  for (int i = 0; i < 4; ++i){
    const int rbase = tm + wm + i * 16 + quad * 4;
#pragma unroll
    for (int j = 0; j < 4; ++j){
      const int col = tn + wn + j * 16 + lrow;
      float cb = 0.f;
      if (BIAS_MODE == 2) cb = bias[col];
#pragma unroll
      for (int r = 0; r < 4; ++r){
        const int row = rbase + r;
        float v = acc[i][j][r];
        if (BIAS_MODE == 1) v += bias[row];
        if (BIAS_MODE == 2) v += cb;
        if (OUT_MODE == 1){
          ((float*)Out)[obase + (long)row * ldo + col] = v;
        } else if (OUT_MODE == 0){
          ((u16*)Out)[obase + (long)row * ldo + col] = f2bf(v);
        } else {
          *(u32*)((u16*)Out + obase + (long)row * ldo + col * 2) = split2(v);
        }
      }
    }
  }
}

// =====================================================================
// Transpose+split chunk: x [CHB,C,N] fp32 -> xT2 [CHB,N,2C] bf16 hi/lo
// =====================================================================
__global__ __launch_bounds__(1024)
void transpose_split_k(const float* __restrict__ x, u32* __restrict__ xT2)
{
  __shared__ float t[32][33];
  const int b  = blockIdx.z;
  const int n0 = blockIdx.x << 5;
  const int c0 = blockIdx.y << 5;
  const float* xb = x + (long)b * ((long)C_ * N_);
  u32* xo = xT2 + (long)b * ((long)N_ * C_);
  t[threadIdx.y][threadIdx.x] = xb[(long)(c0 + threadIdx.y) * N_ + n0 + threadIdx.x];
  __syncthreads();
  xo[(long)(n0 + threadIdx.y) * C_ + c0 + threadIdx.x] = split2(t[threadIdx.x][threadIdx.y]);
}

// =====================================================================
// Weight split: W fp32 [n] -> W2 u32 (bf16 hi|lo)
// =====================================================================
__global__ __launch_bounds__(256)
void wsplit_k(const float* __restrict__ W, u32* __restrict__ W2)
{
  const long i = ((long)blockIdx.x * 256 + threadIdx.x) * 4;
  const float4 v = *(const float4*)(W + i);
  uint4 o;
  o.x = split2(v.x); o.y = split2(v.y); o.z = split2(v.z); o.w = split2(v.w);
  *(uint4*)(W2 + i) = o;
}

// =====================================================================
// Plain fp32 -> bf16 pack (for Wo)
// =====================================================================
__global__ __launch_bounds__(256)
void pack_bf16_k(const float* __restrict__ W, u16* __restrict__ Wb)
{
  const long i = ((long)blockIdx.x * 256 + threadIdx.x) * 8;
  const float4 a = *(const float4*)(W + i);
  const float4 b = *(const float4*)(W + i + 4);
  uint4 o;
  o.x = (u32)f2bf(a.x) | ((u32)f2bf(a.y) << 16);
  o.y = (u32)f2bf(a.z) | ((u32)f2bf(a.w) << 16);
  o.z = (u32)f2bf(b.x) | ((u32)f2bf(b.y) << 16);
  o.w = (u32)f2bf(b.z) | ((u32)f2bf(b.w) << 16);
  *(uint4*)(Wb + i) = o;
}

// =====================================================================
// Row softmax over f [rows, 512] fp32; writes bf16 attn IN PLACE at row
// start (row stride stays 512 floats = 1024 u16).
// =====================================================================
__global__ __launch_bounds__(256)
void softmax_k(float* __restrict__ f)
{
  const long row = blockIdx.x;
  float* fr = f + (row << 9);
  const int tid = threadIdx.x;
  const float v0 = fr[tid];
  const float v1 = fr[tid + 256];

  float m = fmaxf(v0, v1);
#pragma unroll
  for (int off = 32; off; off >>= 1) m = fmaxf(m, __shfl_xor(m, off, 64));
  __shared__ float red[8];
  const int wave = tid >> 6, lane = tid & 63;
  if (!lane) red[wave] = m;
  __syncthreads();
  m = fmaxf(fmaxf(red[0], red[1]), fmaxf(red[2], red[3]));

  const float e0 = __expf(v0 - m);
  const float e1 = __expf(v1 - m);
  float s = e0 + e1;
#pragma unroll
  for (int off = 32; off; off >>= 1) s += __shfl_xor(s, off, 64);
  if (!lane) red[4 + wave] = s;
  __syncthreads();
  const float rs = 1.f / (red[4] + red[5] + red[6] + red[7]);

  u16* ar = (u16*)fr;
  ar[tid]       = f2bf(e0 * rs);
  ar[tid + 256] = f2bf(e1 * rs);
}

// =====================================================================
// BN stats per channel over (b,n): mean | rstd  (wy bf16 [B,C,N])
// =====================================================================
__global__ __launch_bounds__(256)
void bn_stats_k(const u16* __restrict__ wy, float* __restrict__ stats)
{
  const int c = blockIdx.x;
  const int tid = threadIdx.x;
  float s = 0.f, q = 0.f;
  const u16* base = wy + (long)c * N_;
  for (int b = 0; b < B_; ++b){
    const u32 w = ((const u32*)(base + (long)b * ((long)C_ * N_)))[tid];
    const float a0 = bf2f((u16)(w & 0xffff));
    const float a1 = bf2f((u16)(w >> 16));
    s += a0 + a1;
    q += a0 * a0 + a1 * a1;
  }
#pragma unroll
  for (int off = 32; off; off >>= 1){ s += __shfl_xor(s, off, 64); q += __shfl_xor(q, off, 64); }
  __shared__ float rs_[4], rq_[4];
  const int wave = tid >> 6, lane = tid & 63;
  if (!lane){ rs_[wave] = s; rq_[wave] = q; }
  __syncthreads();
  if (tid == 0){
    const float S = rs_[0] + rs_[1] + rs_[2] + rs_[3];
    const float Q = rq_[0] + rq_[1] + rq_[2] + rq_[3];
    const float inv = 1.f / (float)(B_ * N_);
    const float mean = S * inv;
    const float var  = Q * inv - mean * mean;
    stats[c]      = mean;
    stats[C_ + c] = rsqrtf(var + 1e-5f);
  }
}

// =====================================================================
// BN apply + residual: out = (wy-mean)*rstd*gamma + beta + x  (fp32 out)
// =====================================================================
__global__ __launch_bounds__(256)
void bn_apply_k(const u16* __restrict__ wy, const float* __restrict__ x,
                const float* __restrict__ stats,
                const float* __restrict__ gamma, const float* __restrict__ beta,
                float* __restrict__ out)
{
  const long i = ((long)blockIdx.x * 256 + threadIdx.x) * 8;
  const int c = (int)((i >> 9) & (C_ - 1));
  const float a  = stats[C_ + c] * gamma[c];
  const float b0 = beta[c] - stats[c] * a;

  const uint4 wv = *(const uint4*)(wy + i);
  const float4 x0 = *(const float4*)(x + i);
  const float4 x1 = *(const float4*)(x + i + 4);
  float4 o0, o1;
  o0.x = bf2f((u16)(wv.x & 0xffff)) * a + b0 + x0.x;
  o0.y = bf2f((u16)(wv.x >> 16))    * a + b0 + x0.y;
  o0.z = bf2f((u16)(wv.y & 0xffff)) * a + b0 + x0.z;
  o0.w = bf2f((u16)(wv.y >> 16))    * a + b0 + x0.w;
  o1.x = bf2f((u16)(wv.z & 0xffff)) * a + b0 + x1.x;
  o1.y = bf2f((u16)(wv.z >> 16))    * a + b0 + x1.y;
  o1.z = bf2f((u16)(wv.w & 0xffff)) * a + b0 + x1.z;
  o1.w = bf2f((u16)(wv.w >> 16))    * a + b0 + x1.w;
  *(float4*)(out + i)     = o0;
  *(float4*)(out + i + 4) = o1;
}

// =====================================================================
extern "C" void kernel_launch(void* const* d_in, const int* in_sizes, int n_in,
                              void* d_out, int out_size, void* d_ws, size_t ws_size,
                              hipStream_t stream)
{
  (void)in_sizes; (void)n_in; (void)out_size; (void)ws_size;
  const float* x     = (const float*)d_in[0];
  const float* Wg    = (const float*)d_in[1];
  const float* bg    = (const float*)d_in[2];
  const float* Wt    = (const float*)d_in[3];
  const float* bt    = (const float*)d_in[4];
  const float* Wp    = (const float*)d_in[5];
  const float* bp    = (const float*)d_in[6];
  const float* Wo    = (const float*)d_in[7];
  const float* bo    = (const float*)d_in[8];
  const float* gamma = (const float*)d_in[9];
  const float* beta  = (const float*)d_in[10];
  float* out = (float*)d_out;

  // ---- scratch in d_out (fully rewritten by bn_apply at the end) ----
  // xT2 chunk [CHB,N,2C] bf16 pairs : 128 MiB at d_out+0
  // th2 chunk [CHB,N,2Ci]           :  64 MiB at d_out+128M
  // ph2 chunk [CHB,N,2Ci]           :  64 MiB at d_out+192M
  char* ob = (char*)d_out;
  u16* xT2 = (u16*)ob;
  u16* th2 = (u16*)(ob + 134217728L);
  u16* ph2 = (u16*)(ob + 134217728L + 67108864L);

  // ---- d_ws layout (~252 MiB) ----
  char* ws = (char*)d_ws;
  u16*   wy  = (u16*)ws;                         // [B,C,N] bf16  128 MiB
  u16*   g   = (u16*)(ws + 134217728L);          // chunk [CHB,Ci,N] 32 MiB
  float* f   = (float*)(ws + 134217728L + 33554432L);          // chunk 32 MiB
  u16*   yT  = (u16*)(ws + 134217728L + 2*33554432L);          // chunk 32 MiB
  u32*   Wg2 = (u32*)(ws + 134217728L + 3*33554432L);          // 8 MiB
  u32*   Wt2 = Wg2 + 2097152L;                                  // 8 MiB
  u32*   Wp2 = Wt2 + 2097152L;                                  // 8 MiB
  u16*   Wob = (u16*)(Wp2 + 2097152L);                          // 4 MiB
  float* stats = (float*)(Wob + 2097152L);                      // 16 KiB

  // ---- weight conversions (once per launch) ----
  wsplit_k<<<dim3(2097152 / (256 * 4)), 256, 0, stream>>>(Wg, Wg2);
  wsplit_k<<<dim3(2097152 / (256 * 4)), 256, 0, stream>>>(Wt, Wt2);
  wsplit_k<<<dim3(2097152 / (256 * 4)), 256, 0, stream>>>(Wp, Wp2);
  pack_bf16_k<<<dim3(2097152 / (256 * 8)), 256, 0, stream>>>(Wo, Wob);

  const long xBatch   = (long)C_ * N_;      // fp32 elems per batch of x
  const long xt2B     = (long)N_ * 2 * C_;  // u16 per batch
  const long th2B     = (long)N_ * 2 * CI_;
  const long gB       = (long)CI_ * N_;
  const long fB       = (long)N_ * N_;      // fp32
  const long attnB    = (long)N_ * 1024;    // u16 (row stride 1024)
  const long yB       = (long)N_ * CI_;
  const long wyB      = (long)C_ * N_;

  for (int h = 0; h < 2; ++h){
    const float* xc = x + (long)h * CHB * xBatch;

    // 1) transpose + hi/lo split
    transpose_split_k<<<dim3(N_ / 32, C_ / 32, CHB), dim3(32, 32), 0, stream>>>(
        xc, (u32*)xT2);

    // 2) th2[n][2o] = xT2 . Wt2 (pair trick), +bt per col, pair out
    gemm_nt<2, 2, true><<<dim3(N_ / 128, CI_ / 128, CHB), 256, 0, stream>>>(
        xT2, xt2B, 2 * C_, (const u16*)Wt2, 0L, 2 * C_, th2, th2B, 2 * CI_, bt, 2 * C_);

    // 3) ph2 likewise
    gemm_nt<2, 2, true><<<dim3(N_ / 128, CI_ / 128, CHB), 256, 0, stream>>>(
        xT2, xt2B, 2 * C_, (const u16*)Wp2, 0L, 2 * C_, ph2, th2B, 2 * CI_, bp, 2 * C_);

    // 4) g[o][n] = Wg2 . xT2 (pair trick), +bg per row, bf16 out
    gemm_nt<1, 0, true><<<dim3(CI_ / 128, N_ / 128, CHB), 256, 0, stream>>>(
        (const u16*)Wg2, 0L, 2 * C_, xT2, xt2B, 2 * C_, g, gB, N_, bg, 2 * C_);

    // 5) f[n][m] = th2 . ph2 (pair trick), fp32 out
    gemm_nt<0, 1, true><<<dim3(N_ / 128, N_ / 128, CHB), 256, 0, stream>>>(
        th2, th2B, 2 * CI_, ph2, th2B, 2 * CI_, f, fB, N_, nullptr, 2 * CI_);

    // 6) softmax rows -> bf16 attn in place
    softmax_k<<<dim3(CHB * N_), 256, 0, stream>>>(f);

    // 7) yT[n][ci] = attn . g
    gemm_nt<0, 0, false><<<dim3(N_ / 128, CI_ / 128, CHB), 256, 0, stream>>>(
        (const u16*)f, attnB, 1024, g, gB, N_, yT, yB, CI_, nullptr, N_);

    // 8) wy[o][n] = Wob . yT + bo
    gemm_nt<1, 0, false><<<dim3(C_ / 128, N_ / 128, CHB), 256, 0, stream>>>(
        Wob, 0L, CI_, yT, yB, CI_, wy + (long)h * CHB * wyB, wyB, N_, bo, CI_);
  }

  // 9) BN stats per channel (over all B)
  bn_stats_k<<<dim3(C_), 256, 0, stream>>>(wy, stats);

  // 10) BN apply + residual -> fp32 out (overwrites all d_out scratch)
  bn_apply_k<<<dim3((int)(((long)B_ * C_ * N_) / (256 * 8))), 256, 0, stream>>>(
      wy, x, stats, gamma, beta, out);
}